// Round 10
// baseline (307.066 us; speedup 1.0000x reference)
//
#include <hip/hip_runtime.h>

// B=2, S=2048, H=1024, NUM_HEAD=16, HEAD=64
#define BATCH 2
#define S_LEN 2048
#define HDIM  1024
#define NHEAD 16
#define HD    64
#define NEGBIAS -1e10f
#define LOG2E 1.44269504088896f

typedef __attribute__((ext_vector_type(8))) _Float16 half8;  // 8 f16 in 4 VGPRs
typedef __attribute__((ext_vector_type(4))) _Float16 half4;  // 4 f16 in 2 VGPRs
typedef __attribute__((ext_vector_type(4))) float   f32x4;   // MFMA C/D frag
// cvt_pkrtz plumbing uses __fp16 vectors (the builtin's native type)
typedef __attribute__((ext_vector_type(2))) __fp16 fp16x2;
typedef __attribute__((ext_vector_type(4))) __fp16 fp16x4;
typedef __attribute__((ext_vector_type(8))) __fp16 fp16x8;

__device__ __forceinline__ float max3f(float a, float b, float c) {
    return fmaxf(fmaxf(a, b), c);        // clang fuses to v_max3_f32
}

__device__ __forceinline__ half8 pk8(float4 a, float4 b) {
    fp16x2 p0 = __builtin_amdgcn_cvt_pkrtz(a.x, a.y);
    fp16x2 p1 = __builtin_amdgcn_cvt_pkrtz(a.z, a.w);
    fp16x2 p2 = __builtin_amdgcn_cvt_pkrtz(b.x, b.y);
    fp16x2 p3 = __builtin_amdgcn_cvt_pkrtz(b.z, b.w);
    fp16x4 lo = __builtin_shufflevector(p0, p1, 0, 1, 2, 3);
    fp16x4 hi = __builtin_shufflevector(p2, p3, 0, 1, 2, 3);
    fp16x8 v8 = __builtin_shufflevector(lo, hi, 0, 1, 2, 3, 4, 5, 6, 7);
    return __builtin_bit_cast(half8, v8);
}

// ---------------------------------------------------------------------------
// Fused projection GEMM -- EXACT R4 structure (best measured: 80.4us, 322 TF).
// R5-R9 proved the reg-staged 2-phase structure is capped here regardless of
// prefetch depth / barriers / locality / occupancy; keep the best variant.
// Y = X @ W^T + b; z=0,1 -> [B,NH,S,HD]; z=2 -> V^T [B,NH,HD,S].
// 128x128 tile, BK=32, 1-deep register prefetch, pk8 conversion at staging.
// z==0 (Q) output PRE-SCALED by log2(e) so attention can use exp2 directly.
// ---------------------------------------------------------------------------
__global__ __launch_bounds__(256) void proj_gemm_f16(
    const float* __restrict__ Xq, const float* __restrict__ Wq, const float* __restrict__ bq,
    const float* __restrict__ Xk, const float* __restrict__ Wk, const float* __restrict__ bk,
    const float* __restrict__ Xv, const float* __restrict__ Wv, const float* __restrict__ bv,
    _Float16* __restrict__ Qb, _Float16* __restrict__ Kb, _Float16* __restrict__ Vtb)
{
    const int z = blockIdx.z;
    const float* X    = (z == 0) ? Xq : (z == 1) ? Xk : Xv;
    const float* W    = (z == 0) ? Wq : (z == 1) ? Wk : Wv;
    const float* bias = (z == 0) ? bq : (z == 1) ? bk : bv;
    _Float16* Y       = (z == 0) ? Qb : (z == 1) ? Kb : Vtb;

    const int n0 = blockIdx.x * 128;
    const int m0 = blockIdx.y * 128;

    __shared__ __align__(16) _Float16 As[128][40];  // [m][k], pad 40
    __shared__ __align__(16) _Float16 Bs[128][40];  // [n][k]

    const int t    = threadIdx.x;
    const int w    = t >> 6;
    const int lane = t & 63;
    const int quad = lane >> 4;
    const int lc   = lane & 15;
    const int wm   = (w >> 1) * 64;
    const int wn   = (w & 1) * 64;

    const f32x4 fzero = {0.f, 0.f, 0.f, 0.f};
    f32x4 acc[4][4];
#pragma unroll
    for (int i = 0; i < 4; i++)
#pragma unroll
        for (int j2 = 0; j2 < 4; j2++) acc[i][j2] = fzero;

    const int srow = t >> 2;   // 0..63 (two halves: srow, srow+64)
    const int sc   = t & 3;    // 8-elem chunk within the 32-elem k slice

    float4 xa[2][2], wa[2][2];          // 1-deep prefetch registers
#define PROJ_ISSUE(K0)                                                        \
    {                                                                         \
        _Pragma("unroll")                                                     \
        for (int hf = 0; hf < 2; hf++) {                                      \
            const float* gx = X + (size_t)(m0 + srow + hf * 64) * HDIM + (K0) + sc * 8; \
            xa[hf][0] = *(const float4*)gx;                                   \
            xa[hf][1] = *(const float4*)(gx + 4);                             \
            const float* gw = W + (size_t)(n0 + srow + hf * 64) * HDIM + (K0) + sc * 8; \
            wa[hf][0] = *(const float4*)gw;                                   \
            wa[hf][1] = *(const float4*)(gw + 4);                             \
        }                                                                     \
    }

    PROJ_ISSUE(0)

    for (int k0 = 0; k0 < HDIM; k0 += 32) {
        if (k0) __syncthreads();        // prev iter done reading LDS
#pragma unroll
        for (int hf = 0; hf < 2; hf++) {
            int row = srow + hf * 64;
            *(half8*)&As[row][sc * 8] = pk8(xa[hf][0], xa[hf][1]);
            *(half8*)&Bs[row][sc * 8] = pk8(wa[hf][0], wa[hf][1]);
        }
        __syncthreads();

        if (k0 + 32 < HDIM) PROJ_ISSUE(k0 + 32)   // overlap with MFMAs below

        half8 af[4], bf[4];
#pragma unroll
        for (int mt = 0; mt < 4; mt++)
            af[mt] = *(const half8*)&As[wm + mt * 16 + lc][quad * 8];
#pragma unroll
        for (int nt = 0; nt < 4; nt++)
            bf[nt] = *(const half8*)&Bs[wn + nt * 16 + lc][quad * 8];
#pragma unroll
        for (int mt = 0; mt < 4; mt++)
#pragma unroll
            for (int nt = 0; nt < 4; nt++)
                acc[mt][nt] = __builtin_amdgcn_mfma_f32_16x16x32_f16(
                    af[mt], bf[nt], acc[mt][nt], 0, 0, 0);
    }

#pragma unroll
    for (int nt = 0; nt < 4; nt++) {
        const int n = n0 + wn + nt * 16 + lc;          // h*64 + d
        const float bv_ = bias[n];
        const int h = n >> 6, d = n & 63;
#pragma unroll
        for (int mt = 0; mt < 4; mt++) {
#pragma unroll
            for (int r = 0; r < 4; r++) {
                const int m = m0 + wm + mt * 16 + quad * 4 + r;   // b*S + s
                const int b = m >> 11, s = m & (S_LEN - 1);
                const int bh = b * NHEAD + h;
                float y = acc[mt][nt][r] + bv_;
                if (z == 0) y *= LOG2E;                 // exp2-fold for attn
                _Float16 val = (_Float16)y;
                if (z == 2)
                    Y[((size_t)bh * HD + d) * S_LEN + s] = val;          // V^T
                else
                    Y[((size_t)bh * S_LEN + s) * HD + d] = val;          // Q,K
            }
        }
    }
}

// ---------------------------------------------------------------------------
// Flash attention v5 -- BARRIER-FREE.  K/V per head are 256KB each and
// L2-resident under the XCD swizzle (4 heads x 512KB = 2MB per 4MB L2), so
// LDS-staging them is pure overhead (m169 pattern / Common-mistake #7).
//   * kf/vf MFMA fragments read DIRECTLY from global (L1/L2 hits); K is
//     row-major, V already transposed by proj -> fragment order is native.
//   * mask bias from 4 int4 loads per tile, folded into MFMA C-init.
//   * Ks/Vts/biasS LDS deleted; only per-wave Ps remains (18.4KB).
//   * ZERO __syncthreads: 4 waves fully independent; one wave's softmax
//     overlaps another's MFMA.  vf loads issued before softmax (latency
//     hides under it).  s_setprio(1) around MFMA clusters (T5, m191 regime).
// Orientation: S^T = K.Q^T, O^T = V^T.P^T, 128 q-rows/block, 2 qg/wave.
// exp2 log2-domain softmax (Q pre-scaled), defer-max, v_max3 trees, pkrtz.
// ---------------------------------------------------------------------------
__global__ __launch_bounds__(256) void flash_attn_mfma(
    const _Float16* __restrict__ Qb, const _Float16* __restrict__ Kb,
    const _Float16* __restrict__ Vtb, const int* __restrict__ mask,
    float* __restrict__ out)
{
    const int bid = blockIdx.x;                  // 0..511
    const int swz = (bid & 7) * 64 + (bid >> 3);
    const int qt = swz & 15;                     // 16 q-tiles of 128 rows
    const int bh = swz >> 4;                     // 0..31
    const int b  = bh >> 4;
    const int h  = bh & (NHEAD - 1);

    __shared__ __align__(16) _Float16 Ps[4][32][72];   // per-wave P, [q][key]

    const int t    = threadIdx.x;
    const int w    = t >> 6;
    const int lane = t & 63;
    const int quad = lane >> 4;
    const int lc   = lane & 15;

    // per-lane fragment base pointers (fold lc/quad once)
    const _Float16* Kl = Kb  + (size_t)bh * S_LEN * HD + (size_t)lc * HD + quad * 8;
    const _Float16* Vl = Vtb + (size_t)bh * HD * S_LEN + (size_t)lc * S_LEN + quad * 8;
    const int*      ml = mask + b * S_LEN + quad * 4;

    // Q B-frags: qg in {0,1}, q-row = qt*128 + w*32 + qg*16 + lc
    half8 qf[2][2];
#pragma unroll
    for (int qg = 0; qg < 2; qg++) {
        const int qrow = qt * 128 + w * 32 + qg * 16 + lc;
#pragma unroll
        for (int s = 0; s < 2; s++)
            qf[qg][s] = *(const half8*)(Qb + ((size_t)bh * S_LEN + qrow) * HD
                                        + s * 32 + quad * 8);
    }

    f32x4 o[2][4];                      // O^T per qg: d = nt*16+quad*4+r, q = lc
    const f32x4 fzero = {0.f, 0.f, 0.f, 0.f};
#pragma unroll
    for (int qg = 0; qg < 2; qg++)
#pragma unroll
        for (int nt = 0; nt < 4; nt++) o[qg][nt] = fzero;
    float mrun[2] = {-3.0e38f, -3.0e38f};
    float lrun[2] = {0.f, 0.f};

    for (int kt = 0; kt < S_LEN; kt += 64) {
        // mask bias for this key tile (int4 per tt; same for both qg)
        int4 mm[4];
#pragma unroll
        for (int tt = 0; tt < 4; tt++)
            mm[tt] = *(const int4*)(ml + kt + tt * 16);

        // V fragments issued EARLY: in flight across QK^T + softmax
        half8 vfr[2][4];
#pragma unroll
        for (int s = 0; s < 2; s++)
#pragma unroll
            for (int nt = 0; nt < 4; nt++)
                vfr[s][nt] = *(const half8*)(Vl + (size_t)(nt * 16) * S_LEN
                                             + kt + s * 32);

        // S^T = K.Q^T, bias in the MFMA C operand, K frags direct from L2
        f32x4 scf[2][4];
#pragma unroll
        for (int tt = 0; tt < 4; tt++) {
            f32x4 cini;
            cini[0] = mm[tt].x ? 0.f : NEGBIAS;
            cini[1] = mm[tt].y ? 0.f : NEGBIAS;
            cini[2] = mm[tt].z ? 0.f : NEGBIAS;
            cini[3] = mm[tt].w ? 0.f : NEGBIAS;
            scf[0][tt] = cini;
            scf[1][tt] = cini;
        }
        __builtin_amdgcn_s_setprio(1);
#pragma unroll
        for (int s = 0; s < 2; s++) {
#pragma unroll
            for (int tt = 0; tt < 4; tt++) {
                half8 kf = *(const half8*)(Kl + (size_t)(kt + tt * 16) * HD + s * 32);
                scf[0][tt] = __builtin_amdgcn_mfma_f32_16x16x32_f16(kf, qf[0][s], scf[0][tt], 0, 0, 0);
                scf[1][tt] = __builtin_amdgcn_mfma_f32_16x16x32_f16(kf, qf[1][s], scf[1][tt], 0, 0, 0);
            }
        }
        __builtin_amdgcn_s_setprio(0);

        // per-lane online softmax, one q-row per (qg, lc), log2 domain
#pragma unroll
        for (int qg = 0; qg < 2; qg++) {
            const f32x4 a0 = scf[qg][0], a1 = scf[qg][1],
                        a2 = scf[qg][2], a3 = scf[qg][3];
            float m0 = max3f(a0[0], a0[1], a0[2]);
            float m1 = max3f(a0[3], a1[0], a1[1]);
            float m2 = max3f(a1[2], a1[3], a2[0]);
            float m3 = max3f(a2[1], a2[2], a2[3]);
            float m4 = max3f(a3[0], a3[1], a3[2]);
            float mx = fmaxf(max3f(m0, m1, m2), max3f(m3, m4, a3[3]));
            mx = fmaxf(mx, __shfl_xor(mx, 16));
            mx = fmaxf(mx, __shfl_xor(mx, 32));

            // defer-max (T13): skip o-rescale unless max grew past threshold.
            if (!__all(mx <= mrun[qg] + 8.f)) {
                float mn = fmaxf(mrun[qg], mx);
                float al = __builtin_amdgcn_exp2f(mrun[qg] - mn);
                lrun[qg] *= al;
#pragma unroll
                for (int nt = 0; nt < 4; nt++) {
                    o[qg][nt][0] *= al; o[qg][nt][1] *= al;
                    o[qg][nt][2] *= al; o[qg][nt][3] *= al;
                }
                mrun[qg] = mn;
            }

            const float mr = mrun[qg];
            float ps[4][4];
#pragma unroll
            for (int tt = 0; tt < 4; tt++)
#pragma unroll
                for (int r = 0; r < 4; r++) {
                    float p = __builtin_amdgcn_exp2f(scf[qg][tt][r] - mr);
                    ps[tt][r] = p;
                }
            // pairwise sum tree
            float s0 = (ps[0][0] + ps[0][1]) + (ps[0][2] + ps[0][3]);
            float s1 = (ps[1][0] + ps[1][1]) + (ps[1][2] + ps[1][3]);
            float s2 = (ps[2][0] + ps[2][1]) + (ps[2][2] + ps[2][3]);
            float s3 = (ps[3][0] + ps[3][1]) + (ps[3][2] + ps[3][3]);
            float ls = (s0 + s1) + (s2 + s3);
            ls += __shfl_xor(ls, 16);
            ls += __shfl_xor(ls, 32);
            lrun[qg] += ls;

            // P rows (q-major): Ps[w][qg*16+lc][key]; per-wave LDS, no barrier
            // needed (within-wave ds-order via lgkmcnt)
#pragma unroll
            for (int tt = 0; tt < 4; tt++) {
                fp16x2 p01 = __builtin_amdgcn_cvt_pkrtz(ps[tt][0], ps[tt][1]);
                fp16x2 p23 = __builtin_amdgcn_cvt_pkrtz(ps[tt][2], ps[tt][3]);
                fp16x4 pk4 = __builtin_shufflevector(p01, p23, 0, 1, 2, 3);
                *(half4*)&Ps[w][qg * 16 + lc][tt * 16 + quad * 4] =
                    __builtin_bit_cast(half4, pk4);
            }
        }

        // O^T += V^T.P^T : vfr long in flight; each vf feeds both qg MFMAs
        __builtin_amdgcn_s_setprio(1);
#pragma unroll
        for (int s = 0; s < 2; s++) {
            half8 pf0 = *(const half8*)&Ps[w][lc]     [s * 32 + quad * 8];
            half8 pf1 = *(const half8*)&Ps[w][16 + lc][s * 32 + quad * 8];
#pragma unroll
            for (int nt = 0; nt < 4; nt++) {
                o[0][nt] = __builtin_amdgcn_mfma_f32_16x16x32_f16(vfr[s][nt], pf0, o[0][nt], 0, 0, 0);
                o[1][nt] = __builtin_amdgcn_mfma_f32_16x16x32_f16(vfr[s][nt], pf1, o[1][nt], 0, 0, 0);
            }
        }
        __builtin_amdgcn_s_setprio(0);
    }

    // epilogue: lane owns q-row per qg; contiguous float4 stores
#pragma unroll
    for (int qg = 0; qg < 2; qg++) {
        const int qrow = qt * 128 + w * 32 + qg * 16 + lc;
        const float inv = 1.f / lrun[qg];
        const size_t rowb = ((size_t)b * S_LEN + qrow) * HDIM + h * HD;
#pragma unroll
        for (int nt = 0; nt < 4; nt++) {
            float4 v;
            v.x = o[qg][nt][0] * inv; v.y = o[qg][nt][1] * inv;
            v.z = o[qg][nt][2] * inv; v.w = o[qg][nt][3] * inv;
            *(float4*)&out[rowb + nt * 16 + quad * 4] = v;
        }
    }
}

// ---------------------------------------------------------------------------
extern "C" void kernel_launch(void* const* d_in, const int* in_sizes, int n_in,
                              void* d_out, int out_size, void* d_ws, size_t ws_size,
                              hipStream_t stream) {
    const float* query = (const float*)d_in[0];
    const float* key   = (const float*)d_in[1];
    const float* value = (const float*)d_in[2];
    const int*   mask  = (const int*)  d_in[3];
    const float* Wq    = (const float*)d_in[4];
    const float* bq    = (const float*)d_in[5];
    const float* Wk    = (const float*)d_in[6];
    const float* bk    = (const float*)d_in[7];
    const float* Wv    = (const float*)d_in[8];
    const float* bv    = (const float*)d_in[9];
    float* out = (float*)d_out;

    const size_t nElem = (size_t)BATCH * S_LEN * HDIM;          // 4M
    if (ws_size < 3 * nElem * sizeof(_Float16)) return;         // 24 MB
    _Float16* Qb  = (_Float16*)d_ws;
    _Float16* Kb  = Qb + nElem;
    _Float16* Vtb = Kb + nElem;

    dim3 gproj(HDIM / 128, (BATCH * S_LEN) / 128, 3);           // (8, 32, 3)
    proj_gemm_f16<<<gproj, 256, 0, stream>>>(query, Wq, bq, key, Wk, bk,
                                             value, Wv, bv, Qb, Kb, Vtb);

    flash_attn_mfma<<<BATCH * NHEAD * (S_LEN / 128), 256, 0, stream>>>(
        Qb, Kb, Vtb, mask, out);
}

// Round 11
// 235.829 us; speedup vs baseline: 1.3021x; 1.3021x over previous
//
#include <hip/hip_runtime.h>

// B=2, S=2048, H=1024, NUM_HEAD=16, HEAD=64
#define BATCH 2
#define S_LEN 2048
#define HDIM  1024
#define NHEAD 16
#define HD    64
#define NEGBIAS -1e10f
#define LOG2E 1.44269504088896f

typedef __attribute__((ext_vector_type(8))) _Float16 half8;  // 8 f16 in 4 VGPRs
typedef __attribute__((ext_vector_type(4))) _Float16 half4;  // 4 f16 in 2 VGPRs
typedef __attribute__((ext_vector_type(4))) float   f32x4;   // MFMA C/D frag
// cvt_pkrtz plumbing uses __fp16 vectors (the builtin's native type)
typedef __attribute__((ext_vector_type(2))) __fp16 fp16x2;
typedef __attribute__((ext_vector_type(4))) __fp16 fp16x4;
typedef __attribute__((ext_vector_type(8))) __fp16 fp16x8;

__device__ __forceinline__ float max3f(float a, float b, float c) {
    return fmaxf(fmaxf(a, b), c);        // clang fuses to v_max3_f32
}

__device__ __forceinline__ half8 pk8(float4 a, float4 b) {
    fp16x2 p0 = __builtin_amdgcn_cvt_pkrtz(a.x, a.y);
    fp16x2 p1 = __builtin_amdgcn_cvt_pkrtz(a.z, a.w);
    fp16x2 p2 = __builtin_amdgcn_cvt_pkrtz(b.x, b.y);
    fp16x2 p3 = __builtin_amdgcn_cvt_pkrtz(b.z, b.w);
    fp16x4 lo = __builtin_shufflevector(p0, p1, 0, 1, 2, 3);
    fp16x4 hi = __builtin_shufflevector(p2, p3, 0, 1, 2, 3);
    fp16x8 v8 = __builtin_shufflevector(lo, hi, 0, 1, 2, 3, 4, 5, 6, 7);
    return __builtin_bit_cast(half8, v8);
}

__device__ __forceinline__ half4 pk4(float a, float b, float c, float d) {
    fp16x2 p01 = __builtin_amdgcn_cvt_pkrtz(a, b);
    fp16x2 p23 = __builtin_amdgcn_cvt_pkrtz(c, d);
    fp16x4 v = __builtin_shufflevector(p01, p23, 0, 1, 2, 3);
    return __builtin_bit_cast(half4, v);
}

// ---------------------------------------------------------------------------
// Fused projection GEMM -- R4 structure (best measured: 80.4us / 322 TF; the
// 2-phase reg-staged ceiling for this shape per R5-R9 ablations).
// Y = X @ W^T + b; z=0,1 -> [B,NH,S,HD]; z=2 -> V^T [B,NH,HD,S].
// 128x128 tile, BK=32, 1-deep register prefetch, pk8 conversion at staging.
// R11 delta: z==2 epilogue packs the 4 s-consecutive r-values into one
// 8B store (64 scattered 2B stores -> 16 packed 8B stores).
// z==0 (Q) output PRE-SCALED by log2(e) so attention can use exp2 directly.
// ---------------------------------------------------------------------------
__global__ __launch_bounds__(256) void proj_gemm_f16(
    const float* __restrict__ Xq, const float* __restrict__ Wq, const float* __restrict__ bq,
    const float* __restrict__ Xk, const float* __restrict__ Wk, const float* __restrict__ bk,
    const float* __restrict__ Xv, const float* __restrict__ Wv, const float* __restrict__ bv,
    _Float16* __restrict__ Qb, _Float16* __restrict__ Kb, _Float16* __restrict__ Vtb)
{
    const int z = blockIdx.z;
    const float* X    = (z == 0) ? Xq : (z == 1) ? Xk : Xv;
    const float* W    = (z == 0) ? Wq : (z == 1) ? Wk : Wv;
    const float* bias = (z == 0) ? bq : (z == 1) ? bk : bv;
    _Float16* Y       = (z == 0) ? Qb : (z == 1) ? Kb : Vtb;

    const int n0 = blockIdx.x * 128;
    const int m0 = blockIdx.y * 128;

    __shared__ __align__(16) _Float16 As[128][40];  // [m][k], pad 40
    __shared__ __align__(16) _Float16 Bs[128][40];  // [n][k]

    const int t    = threadIdx.x;
    const int w    = t >> 6;
    const int lane = t & 63;
    const int quad = lane >> 4;
    const int lc   = lane & 15;
    const int wm   = (w >> 1) * 64;
    const int wn   = (w & 1) * 64;

    const f32x4 fzero = {0.f, 0.f, 0.f, 0.f};
    f32x4 acc[4][4];
#pragma unroll
    for (int i = 0; i < 4; i++)
#pragma unroll
        for (int j2 = 0; j2 < 4; j2++) acc[i][j2] = fzero;

    const int srow = t >> 2;   // 0..63 (two halves: srow, srow+64)
    const int sc   = t & 3;    // 8-elem chunk within the 32-elem k slice

    float4 xa[2][2], wa[2][2];          // 1-deep prefetch registers
#define PROJ_ISSUE(K0)                                                        \
    {                                                                         \
        _Pragma("unroll")                                                     \
        for (int hf = 0; hf < 2; hf++) {                                      \
            const float* gx = X + (size_t)(m0 + srow + hf * 64) * HDIM + (K0) + sc * 8; \
            xa[hf][0] = *(const float4*)gx;                                   \
            xa[hf][1] = *(const float4*)(gx + 4);                             \
            const float* gw = W + (size_t)(n0 + srow + hf * 64) * HDIM + (K0) + sc * 8; \
            wa[hf][0] = *(const float4*)gw;                                   \
            wa[hf][1] = *(const float4*)(gw + 4);                             \
        }                                                                     \
    }

    PROJ_ISSUE(0)

    for (int k0 = 0; k0 < HDIM; k0 += 32) {
        if (k0) __syncthreads();        // prev iter done reading LDS
#pragma unroll
        for (int hf = 0; hf < 2; hf++) {
            int row = srow + hf * 64;
            *(half8*)&As[row][sc * 8] = pk8(xa[hf][0], xa[hf][1]);
            *(half8*)&Bs[row][sc * 8] = pk8(wa[hf][0], wa[hf][1]);
        }
        __syncthreads();

        if (k0 + 32 < HDIM) PROJ_ISSUE(k0 + 32)   // overlap with MFMAs below

        half8 af[4], bf[4];
#pragma unroll
        for (int mt = 0; mt < 4; mt++)
            af[mt] = *(const half8*)&As[wm + mt * 16 + lc][quad * 8];
#pragma unroll
        for (int nt = 0; nt < 4; nt++)
            bf[nt] = *(const half8*)&Bs[wn + nt * 16 + lc][quad * 8];
#pragma unroll
        for (int mt = 0; mt < 4; mt++)
#pragma unroll
            for (int nt = 0; nt < 4; nt++)
                acc[mt][nt] = __builtin_amdgcn_mfma_f32_16x16x32_f16(
                    af[mt], bf[nt], acc[mt][nt], 0, 0, 0);
    }

#pragma unroll
    for (int nt = 0; nt < 4; nt++) {
        const int n = n0 + wn + nt * 16 + lc;          // h*64 + d
        const float bv_ = bias[n];
        const int h = n >> 6, d = n & 63;
#pragma unroll
        for (int mt = 0; mt < 4; mt++) {
            if (z == 2) {
                // V^T: r-values are s-consecutive -> one packed 8B store
                const int m = m0 + wm + mt * 16 + quad * 4;       // b*S + s
                const int b = m >> 11, s = m & (S_LEN - 1);
                const int bh = b * NHEAD + h;
                half4 v = pk4(acc[mt][nt][0] + bv_, acc[mt][nt][1] + bv_,
                              acc[mt][nt][2] + bv_, acc[mt][nt][3] + bv_);
                *(half4*)&Vtb[((size_t)bh * HD + d) * S_LEN + s] = v;
            } else {
#pragma unroll
                for (int r = 0; r < 4; r++) {
                    const int m = m0 + wm + mt * 16 + quad * 4 + r;   // b*S + s
                    const int b = m >> 11, s = m & (S_LEN - 1);
                    const int bh = b * NHEAD + h;
                    float y = acc[mt][nt][r] + bv_;
                    if (z == 0) y *= LOG2E;             // exp2-fold for attn
                    Y[((size_t)bh * S_LEN + s) * HD + d] = (_Float16)y;
                }
            }
        }
    }
}

// ---------------------------------------------------------------------------
// Flash attention v6 = R4 structure (best measured ~75us) with one deletion:
// the biasS LDS round-trip (divergent t<64 write + float4 read) is replaced
// by per-lane int4 mask loads folded into the MFMA C-init (pattern verified
// correct in R10).  Everything else identical to R4:
// padded [64][72] LDS staging (immediate offsets), exp2 log2-domain softmax
// (Q pre-scaled), v_max3 trees, cvt_pkrtz packed P, defer-max (T13),
// XCD-aware block swizzle.  S^T = K.Q^T, O^T = V^T.P^T, 128 q-rows/block,
// 4 waves, 2 q-groups/wave (each K/V LDS read feeds 2 MFMAs -- the 4x
// amortization R10 proved is load-bearing).
// ---------------------------------------------------------------------------
__global__ __launch_bounds__(256) void flash_attn_mfma(
    const _Float16* __restrict__ Qb, const _Float16* __restrict__ Kb,
    const _Float16* __restrict__ Vtb, const int* __restrict__ mask,
    float* __restrict__ out)
{
    const int bid = blockIdx.x;                  // 0..511
    const int swz = (bid & 7) * 64 + (bid >> 3);
    const int qt = swz & 15;                     // 16 q-tiles of 128 rows
    const int bh = swz >> 4;                     // 0..31
    const int b  = bh >> 4;
    const int h  = bh & (NHEAD - 1);

    __shared__ __align__(16) _Float16 Ks [64][72];      // [key][d]
    __shared__ __align__(16) _Float16 Vts[64][72];      // [d][key]
    __shared__ __align__(16) _Float16 Ps [4][32][72];   // per-wave P, [q][key]

    const int t    = threadIdx.x;
    const int w    = t >> 6;
    const int lane = t & 63;
    const int quad = lane >> 4;
    const int lc   = lane & 15;

    const _Float16* Kbase = Kb  + (size_t)bh * S_LEN * HD;
    const _Float16* Vbase = Vtb + (size_t)bh * HD * S_LEN;
    const int*      ml    = mask + b * S_LEN + quad * 4;   // per-lane mask base

    // Q B-frags: qg in {0,1}, q-row = qt*128 + w*32 + qg*16 + lc
    half8 qf[2][2];
#pragma unroll
    for (int qg = 0; qg < 2; qg++) {
        const int qrow = qt * 128 + w * 32 + qg * 16 + lc;
#pragma unroll
        for (int s = 0; s < 2; s++)
            qf[qg][s] = *(const half8*)(Qb + ((size_t)bh * S_LEN + qrow) * HD
                                        + s * 32 + quad * 8);
    }

    f32x4 o[2][4];                      // O^T per qg: d = nt*16+quad*4+r, q = lc
    const f32x4 fzero = {0.f, 0.f, 0.f, 0.f};
#pragma unroll
    for (int qg = 0; qg < 2; qg++)
#pragma unroll
        for (int nt = 0; nt < 4; nt++) o[qg][nt] = fzero;
    float mrun[2] = {-3.0e38f, -3.0e38f};
    float lrun[2] = {0.f, 0.f};

    // staging geometry: chunk c = t + 256*i -> row c>>3, col (c&7)*8
    const int rr0 = t >> 3,          cc0 = (t & 7) * 8;
    const int rr1 = (t + 256) >> 3;                       // rows 32..63

    half8 kpre[2], vpre[2];
#define ATTN_ISSUE(KT)                                                        \
    {                                                                         \
        kpre[0] = *(const half8*)(Kbase + (size_t)((KT) + rr0) * HD + cc0);   \
        kpre[1] = *(const half8*)(Kbase + (size_t)((KT) + rr1) * HD + cc0);   \
        vpre[0] = *(const half8*)(Vbase + (size_t)rr0 * S_LEN + (KT) + cc0);  \
        vpre[1] = *(const half8*)(Vbase + (size_t)rr1 * S_LEN + (KT) + cc0);  \
    }

    ATTN_ISSUE(0)

    for (int kt = 0; kt < S_LEN; kt += 64) {
        if (kt) __syncthreads();        // prev iter done reading LDS
        *(half8*)&Ks [rr0][cc0] = kpre[0];
        *(half8*)&Ks [rr1][cc0] = kpre[1];
        *(half8*)&Vts[rr0][cc0] = vpre[0];
        *(half8*)&Vts[rr1][cc0] = vpre[1];
        __syncthreads();

        if (kt + 64 < S_LEN) ATTN_ISSUE(kt + 64)   // overlap with compute

        // mask bias per lane: score (tt,r) is key tt*16+quad*4+r
        int4 mm[4];
#pragma unroll
        for (int tt = 0; tt < 4; tt++)
            mm[tt] = *(const int4*)(ml + kt + tt * 16);

        // S^T = K.Q^T, mask bias pre-loaded into the MFMA C operand.
        f32x4 scf[2][4];
#pragma unroll
        for (int tt = 0; tt < 4; tt++) {
            f32x4 cini;
            cini[0] = mm[tt].x ? 0.f : NEGBIAS;
            cini[1] = mm[tt].y ? 0.f : NEGBIAS;
            cini[2] = mm[tt].z ? 0.f : NEGBIAS;
            cini[3] = mm[tt].w ? 0.f : NEGBIAS;
            scf[0][tt] = cini;
            scf[1][tt] = cini;
        }
#pragma unroll
        for (int s = 0; s < 2; s++) {
#pragma unroll
            for (int tt = 0; tt < 4; tt++) {
                half8 kf = *(const half8*)&Ks[tt * 16 + lc][s * 32 + quad * 8];
                scf[0][tt] = __builtin_amdgcn_mfma_f32_16x16x32_f16(kf, qf[0][s], scf[0][tt], 0, 0, 0);
                scf[1][tt] = __builtin_amdgcn_mfma_f32_16x16x32_f16(kf, qf[1][s], scf[1][tt], 0, 0, 0);
            }
        }

        // per-lane online softmax, one q-row per (qg, lc), log2 domain
#pragma unroll
        for (int qg = 0; qg < 2; qg++) {
            const f32x4 a0 = scf[qg][0], a1 = scf[qg][1],
                        a2 = scf[qg][2], a3 = scf[qg][3];
            float m0 = max3f(a0[0], a0[1], a0[2]);
            float m1 = max3f(a0[3], a1[0], a1[1]);
            float m2 = max3f(a1[2], a1[3], a2[0]);
            float m3 = max3f(a2[1], a2[2], a2[3]);
            float m4 = max3f(a3[0], a3[1], a3[2]);
            float mx = fmaxf(max3f(m0, m1, m2), max3f(m3, m4, a3[3]));
            mx = fmaxf(mx, __shfl_xor(mx, 16));
            mx = fmaxf(mx, __shfl_xor(mx, 32));

            // defer-max (T13): skip o-rescale unless max grew past threshold.
            if (!__all(mx <= mrun[qg] + 8.f)) {
                float mn = fmaxf(mrun[qg], mx);
                float al = __builtin_amdgcn_exp2f(mrun[qg] - mn);
                lrun[qg] *= al;
#pragma unroll
                for (int nt = 0; nt < 4; nt++) {
                    o[qg][nt][0] *= al; o[qg][nt][1] *= al;
                    o[qg][nt][2] *= al; o[qg][nt][3] *= al;
                }
                mrun[qg] = mn;
            }

            const float mr = mrun[qg];
            float ps[4][4];
#pragma unroll
            for (int tt = 0; tt < 4; tt++)
#pragma unroll
                for (int r = 0; r < 4; r++) {
                    float p = __builtin_amdgcn_exp2f(scf[qg][tt][r] - mr);
                    ps[tt][r] = p;
                }
            // pairwise sum tree
            float s0 = (ps[0][0] + ps[0][1]) + (ps[0][2] + ps[0][3]);
            float s1 = (ps[1][0] + ps[1][1]) + (ps[1][2] + ps[1][3]);
            float s2 = (ps[2][0] + ps[2][1]) + (ps[2][2] + ps[2][3]);
            float s3 = (ps[3][0] + ps[3][1]) + (ps[3][2] + ps[3][3]);
            float ls = (s0 + s1) + (s2 + s3);
            ls += __shfl_xor(ls, 16);
            ls += __shfl_xor(ls, 32);
            lrun[qg] += ls;

            // P rows (q-major): Ps[w][qg*16+lc][key], packed RTZ conversion
#pragma unroll
            for (int tt = 0; tt < 4; tt++) {
                *(half4*)&Ps[w][qg * 16 + lc][tt * 16 + quad * 4] =
                    pk4(ps[tt][0], ps[tt][1], ps[tt][2], ps[tt][3]);
            }
        }

        // O^T += V^T.P^T : each vf read feeds both qg MFMAs
#pragma unroll
        for (int s = 0; s < 2; s++) {
            half8 pf0 = *(const half8*)&Ps[w][lc]     [s * 32 + quad * 8];
            half8 pf1 = *(const half8*)&Ps[w][16 + lc][s * 32 + quad * 8];
#pragma unroll
            for (int nt = 0; nt < 4; nt++) {
                half8 vf = *(const half8*)&Vts[nt * 16 + lc][s * 32 + quad * 8];
                o[0][nt] = __builtin_amdgcn_mfma_f32_16x16x32_f16(vf, pf0, o[0][nt], 0, 0, 0);
                o[1][nt] = __builtin_amdgcn_mfma_f32_16x16x32_f16(vf, pf1, o[1][nt], 0, 0, 0);
            }
        }
    }

    // epilogue: lane owns q-row per qg; contiguous float4 stores
#pragma unroll
    for (int qg = 0; qg < 2; qg++) {
        const int qrow = qt * 128 + w * 32 + qg * 16 + lc;
        const float inv = 1.f / lrun[qg];
        const size_t rowb = ((size_t)b * S_LEN + qrow) * HDIM + h * HD;
#pragma unroll
        for (int nt = 0; nt < 4; nt++) {
            float4 v;
            v.x = o[qg][nt][0] * inv; v.y = o[qg][nt][1] * inv;
            v.z = o[qg][nt][2] * inv; v.w = o[qg][nt][3] * inv;
            *(float4*)&out[rowb + nt * 16 + quad * 4] = v;
        }
    }
}

// ---------------------------------------------------------------------------
extern "C" void kernel_launch(void* const* d_in, const int* in_sizes, int n_in,
                              void* d_out, int out_size, void* d_ws, size_t ws_size,
                              hipStream_t stream) {
    const float* query = (const float*)d_in[0];
    const float* key   = (const float*)d_in[1];
    const float* value = (const float*)d_in[2];
    const int*   mask  = (const int*)  d_in[3];
    const float* Wq    = (const float*)d_in[4];
    const float* bq    = (const float*)d_in[5];
    const float* Wk    = (const float*)d_in[6];
    const float* bk    = (const float*)d_in[7];
    const float* Wv    = (const float*)d_in[8];
    const float* bv    = (const float*)d_in[9];
    float* out = (float*)d_out;

    const size_t nElem = (size_t)BATCH * S_LEN * HDIM;          // 4M
    if (ws_size < 3 * nElem * sizeof(_Float16)) return;         // 24 MB
    _Float16* Qb  = (_Float16*)d_ws;
    _Float16* Kb  = Qb + nElem;
    _Float16* Vtb = Kb + nElem;

    dim3 gproj(HDIM / 128, (BATCH * S_LEN) / 128, 3);           // (8, 32, 3)
    proj_gemm_f16<<<gproj, 256, 0, stream>>>(query, Wq, bq, key, Wk, bk,
                                             value, Wv, bv, Qb, Kb, Vtb);

    flash_attn_mfma<<<BATCH * NHEAD * (S_LEN / 128), 256, 0, stream>>>(
        Qb, Kb, Vtb, mask, out);
}